// Round 10
// baseline (170.855 us; speedup 1.0000x reference)
//
#include <hip/hip_runtime.h>

#define NTOK 8192
#define HDIM 4096
#define NEXP 64
#define CAP  160      // int(8192 * 1.25 / 64)
#define KSPLIT 8
#define KPART (HDIM / KSPLIT)   // 512
#define KC   64                 // k per LDS chunk
#define NCH  (KPART / KC)       // 8 chunks

__device__ __forceinline__ unsigned int flip_key(float f) {
    unsigned int u = __float_as_uint(f);
    return u ^ (unsigned int)(((int)u >> 31) | 0x80000000);
}

// ---- Kernel 0: w -> wd2 (fp64, repacked [k4][e][ksub]) + zero mask + loss ----
__global__ __launch_bounds__(256) void conv_w(const float* __restrict__ w,
                                              double* __restrict__ wd2,
                                              float* __restrict__ out_mask,
                                              float* __restrict__ out_loss) {
    int i = blockIdx.x * 256 + threadIdx.x;   // grid 1024 -> 262144
    int k = i >> 6, e = i & 63;
    wd2[((size_t)(k >> 2) * NEXP + e) * 4 + (k & 3)] = (double)w[i];
    if (i < NTOK * NEXP / 4)
        ((float4*)out_mask)[i] = float4{0.f, 0.f, 0.f, 0.f};
    // loss structurally 0: every expert load == CAP; logf(1.0f + 1e-8f) == 0 in fp32
    if (i == 0) out_loss[0] = 0.0f;
}

// ---- Kernel 1: GEMM, lane=token, w via contiguous scalar loads ----
// grid 1024 = 128 token-groups x KSPLIT(8). block 512 = 8 waves; wave wv ->
// experts [wv*8, wv*8+8), lanes = tokens tg0..tg0+63. x fp32 in LDS (swizzled).
__global__ __launch_bounds__(512) void gemm_c(const float* __restrict__ x,
                                              const double* __restrict__ wd2,
                                              double* __restrict__ p) {
    __shared__ float4 xs4[2][64 * 16];   // 2 x 16 KB
    const int tid = threadIdx.x;
    const int l   = tid & 63;
    const int wv  = __builtin_amdgcn_readfirstlane(tid >> 6);  // 0..7, uniform
    const int e0  = wv * 8;
    const int tokgrp = blockIdx.x >> 3;
    const int ks     = blockIdx.x & 7;
    const int tg0    = tokgrp * 64;
    const int kbase  = ks * KPART;

    const float4* x4 = (const float4*)x;

    double acc[8] = {0, 0, 0, 0, 0, 0, 0, 0};

    // staging: 1024 float4 per chunk, 512 threads -> 2 each
    const int t0s = tid >> 4,          c0s = tid & 15;
    const int t1s = (tid + 512) >> 4,  c1s = tid & 15;
    const int d0  = t0s * 16 + (c0s ^ (t0s & 7));
    const int d1  = t1s * 16 + (c1s ^ (t1s & 7));
    const size_t rs = HDIM / 4;

    xs4[0][d0] = x4[(size_t)(tg0 + t0s) * rs + (kbase >> 2) + c0s];
    xs4[0][d1] = x4[(size_t)(tg0 + t1s) * rs + (kbase >> 2) + c1s];

    for (int ch = 0; ch < NCH; ++ch) {
        __syncthreads();
        const int cur = ch & 1;
        const int k0  = kbase + ch * KC;

        // T14: issue next chunk's global loads BEFORE compute
        float4 r0, r1;
        const bool more = (ch + 1 < NCH);
        if (more) {
            int kn = k0 + KC;
            r0 = x4[(size_t)(tg0 + t0s) * rs + (kn >> 2) + c0s];
            r1 = x4[(size_t)(tg0 + t1s) * rs + (kn >> 2) + c1s];
        }

        #pragma unroll 4
        for (int c4 = 0; c4 < 16; ++c4) {
            float4 f = xs4[cur][l * 16 + (c4 ^ (l & 7))];   // b128
            double dx0 = (double)f.x, dx1 = (double)f.y;
            double dx2 = (double)f.z, dx3 = (double)f.w;
            // 32 contiguous doubles (256 B): experts e0..e0+7 x ksub 0..3
            const double* wb = wd2 + ((size_t)((k0 >> 2) + c4) * NEXP + e0) * 4;
            #pragma unroll
            for (int j = 0; j < 8; ++j) {
                acc[j] = fma(dx0, wb[j * 4 + 0], acc[j]);
                acc[j] = fma(dx1, wb[j * 4 + 1], acc[j]);
                acc[j] = fma(dx2, wb[j * 4 + 2], acc[j]);
                acc[j] = fma(dx3, wb[j * 4 + 3], acc[j]);
            }
        }

        if (more) {
            xs4[cur ^ 1][d0] = r0;
            xs4[cur ^ 1][d1] = r1;
        }
    }

    #pragma unroll
    for (int j = 0; j < 8; ++j)
        p[((size_t)ks * NEXP + e0 + j) * NTOK + tg0 + l] = acc[j];
}

// ---- Kernel 2: per-expert top-CAP (sums KSPLIT partials inline; proven core) ----
// 64 blocks (1/expert), 256 threads. Thread t owns tokens [t*32, t*32+32).
__global__ __launch_bounds__(256) void topk_kernel(const double* __restrict__ p,
                                                   float* __restrict__ out_idx,
                                                   float* __restrict__ out_mask) {
    const int e    = blockIdx.x;
    const int tid  = threadIdx.x;
    const int lane = tid & 63;
    const int wv   = tid >> 6;
    const size_t S = (size_t)NEXP * NTOK;

    unsigned int k32[32];
    {
        const double* pr = p + (size_t)e * NTOK + tid * 32;
        #pragma unroll
        for (int j = 0; j < 32; ++j) {
            double s = ((pr[j] + pr[S + j]) + (pr[2 * S + j] + pr[3 * S + j]))
                     + ((pr[4 * S + j] + pr[5 * S + j]) + (pr[6 * S + j] + pr[7 * S + j]));
            k32[j] = flip_key((float)s);
        }
    }

    __shared__ int scnt[4];

    // MSB-first greedy: pth = CAP-th largest key
    unsigned int pth = 0;
    for (int b = 31; b >= 0; --b) {
        unsigned int cand = pth | (1u << b);
        int cl = 0;
        #pragma unroll
        for (int j = 0; j < 32; ++j) cl += (k32[j] >= cand);
        #pragma unroll
        for (int off = 32; off > 0; off >>= 1) cl += __shfl_xor(cl, off);
        if (lane == 0) scnt[wv] = cl;
        __syncthreads();
        int c = scnt[0] + scnt[1] + scnt[2] + scnt[3];
        if (c >= CAP) pth = cand;
        __syncthreads();
    }

    int gl = 0;
    #pragma unroll
    for (int j = 0; j < 32; ++j) gl += (k32[j] > pth);
    #pragma unroll
    for (int off = 32; off > 0; off >>= 1) gl += __shfl_xor(gl, off);
    if (lane == 0) scnt[wv] = gl;
    __syncthreads();
    int g = scnt[0] + scnt[1] + scnt[2] + scnt[3];

    // equals: (CAP-g) smallest token ids among key==pth (stable top_k tie rule)
    __shared__ int eqn, eqm;
    __shared__ int eqtok[192];
    if (tid == 0) eqn = 0;
    __syncthreads();
    #pragma unroll
    for (int j = 0; j < 32; ++j)
        if (k32[j] == pth) {
            int pos = atomicAdd(&eqn, 1);
            if (pos < 192) eqtok[pos] = tid * 32 + j;
        }
    __syncthreads();
    if (tid == 0) {
        int n = eqn < 192 ? eqn : 192;
        for (int a = 0; a < n; ++a)
            for (int b2 = a + 1; b2 < n; ++b2)
                if (eqtok[b2] < eqtok[a]) { int t2 = eqtok[a]; eqtok[a] = eqtok[b2]; eqtok[b2] = t2; }
        eqm = CAP - g;
    }
    __syncthreads();
    const int m = eqm;

    __shared__ unsigned long long sk[256];
    __shared__ int snum;
    if (tid == 0) snum = 0;
    sk[tid] = 0ULL;
    __syncthreads();
    #pragma unroll
    for (int j = 0; j < 32; ++j) {
        int tok = tid * 32 + j;
        bool sel = (k32[j] > pth);
        if (!sel && k32[j] == pth)
            for (int a = 0; a < m; ++a) sel = sel || (eqtok[a] == tok);
        if (sel) {
            int pos = atomicAdd(&snum, 1);
            sk[pos] = ((unsigned long long)k32[j] << 13) | (unsigned int)(8191 - tok);
        }
    }
    __syncthreads();

    // bitonic sort 256 desc (key desc, tie -> smaller token first)
    for (int size = 2; size <= 256; size <<= 1) {
        for (int stride = size >> 1; stride > 0; stride >>= 1) {
            int i = tid, jj = i ^ stride;
            if (jj > i) {
                unsigned long long a = sk[i], b2 = sk[jj];
                bool desc = ((i & size) == 0);
                if (desc ? (a < b2) : (a > b2)) { sk[i] = b2; sk[jj] = a; }
            }
            __syncthreads();
        }
    }

    if (tid < CAP) {
        int tok = 8191 - (int)(sk[tid] & 0x1FFFULL);
        out_idx[e * CAP + tid] = (float)tok;
        out_mask[(size_t)tok * NEXP + e] = 1.0f;
    }
}

extern "C" void kernel_launch(void* const* d_in, const int* in_sizes, int n_in,
                              void* d_out, int out_size, void* d_ws, size_t ws_size,
                              hipStream_t stream) {
    const float* x = (const float*)d_in[0];
    const float* w = (const float*)d_in[1];

    float* out      = (float*)d_out;
    float* out_idx  = out;                            // [64][160]
    float* out_mask = out + NEXP * CAP;               // [8192][64]
    float* out_loss = out + NEXP * CAP + NTOK * NEXP; // [1]

    double* wd2 = (double*)d_ws;                 // 2 MB repacked fp64 w
    double* p   = wd2 + (size_t)HDIM * NEXP;     // 32 MB partials [8][64][8192]

    conv_w<<<HDIM * NEXP / 256, 256, 0, stream>>>(w, wd2, out_mask, out_loss);
    gemm_c<<<1024, 512, 0, stream>>>(x, wd2, p);
    topk_kernel<<<NEXP, 256, 0, stream>>>(p, out_idx, out_mask);
}